// Round 1
// baseline (3111.223 us; speedup 1.0000x reference)
//
#include <hip/hip_runtime.h>

// Problem constants (match setup_inputs)
#define NN 50000      // nodes
#define NE 800000     // edges
#define DNODE 192
#define DEDGE 64
#define DIN 256       // 192 + 64
#define DOUT 256

// ---------------------------------------------------------------------------
// ws layout (floats): h [NN*256] | odeg [NN] | ideg [NN]
// Zero region covers all of it: NN*258 floats.
// ---------------------------------------------------------------------------

__global__ __launch_bounds__(256) void zero_kernel(float4* __restrict__ p, int n4) {
    int i = blockIdx.x * 256 + threadIdx.x;
    if (i < n4) p[i] = make_float4(0.f, 0.f, 0.f, 0.f);
}

__global__ __launch_bounds__(256) void degree_kernel(const int* __restrict__ src,
                                                     const int* __restrict__ dst,
                                                     float* __restrict__ odeg,
                                                     float* __restrict__ ideg) {
    int e = blockIdx.x * 256 + threadIdx.x;
    if (e < NE) {
        atomicAdd(odeg + src[e], 1.0f);
        atomicAdd(ideg + dst[e], 1.0f);
    }
}

// In-place: deg -> rsqrt(max(deg,1)). Covers odeg and ideg (contiguous, 2*NN).
__global__ __launch_bounds__(256) void norm_kernel(float* __restrict__ deg, int n) {
    int i = blockIdx.x * 256 + threadIdx.x;
    if (i < n) deg[i] = rsqrtf(fmaxf(deg[i], 1.0f));
}

// One thread per (edge, 4-col group). 64 float4 groups cover the 256 message
// cols: groups 0..47 come from feat_n[src], 48..63 from edge_feat[e].
// h[dst*256 + c*4 .. +3] += value  (4 scalar fp32 atomics).
__global__ __launch_bounds__(256) void scatter_kernel(const float* __restrict__ feat,
                                                      const float* __restrict__ edge_feat,
                                                      const int* __restrict__ src,
                                                      const int* __restrict__ dst,
                                                      const float* __restrict__ inv_out,
                                                      float* __restrict__ h) {
    int gid = blockIdx.x * 256 + threadIdx.x;
    if (gid >= NE * 64) return;
    int e = gid >> 6;
    int c = gid & 63;                      // float4 index within the 256-col row
    int d = dst[e];
    float4 v;
    if (c < 48) {
        int s = src[e];
        v = ((const float4*)feat)[s * 48 + c];
        float sc = inv_out[s];
        v.x *= sc; v.y *= sc; v.z *= sc; v.w *= sc;
    } else {
        v = ((const float4*)edge_feat)[e * 16 + (c - 48)];
    }
    float* hp = h + d * 256 + c * 4;       // same formula both branches (192 == 48*4)
    atomicAdd(hp + 0, v.x);
    atomicAdd(hp + 1, v.y);
    atomicAdd(hp + 2, v.z);
    atomicAdd(hp + 3, v.w);
}

// rst = (h @ W) * inv_in[:,None] + bias
// Block: 32 rows x 256 cols. 256 threads: rg = tid>>5 (4 rows each),
// cg = tid&31 (8 cols each) -> 32 outputs/thread.
// h tile staged in LDS with pad-260 stride (breaks the 32-bank power-of-2
// conflict on the column walk).
#define HPAD 260
__global__ __launch_bounds__(256) void gemm_kernel(const float* __restrict__ h,
                                                   const float* __restrict__ W,
                                                   const float* __restrict__ bias,
                                                   const float* __restrict__ inv_in,
                                                   float* __restrict__ out) {
    __shared__ float hs[32 * HPAD];
    int block_row = blockIdx.x * 32;

    // Stage 32x256 h tile (float4 granularity: 32 rows x 64 f4)
    for (int i = threadIdx.x; i < 32 * 64; i += 256) {
        int r = i >> 6, c4 = i & 63;
        int row = block_row + r;
        float4 v = make_float4(0.f, 0.f, 0.f, 0.f);
        if (row < NN) v = ((const float4*)h)[row * 64 + c4];
        *(float4*)&hs[r * HPAD + c4 * 4] = v;
    }
    __syncthreads();

    int cg = threadIdx.x & 31;   // cols cg*8 .. cg*8+7
    int rg = threadIdx.x >> 5;   // rows rg*4 .. rg*4+3

    float acc[4][8];
#pragma unroll
    for (int i = 0; i < 4; ++i)
#pragma unroll
        for (int j = 0; j < 8; ++j) acc[i][j] = 0.f;

    const float4* W4 = (const float4*)W;
    for (int k = 0; k < DIN; ++k) {
        float4 w0 = W4[k * 64 + cg * 2];
        float4 w1 = W4[k * 64 + cg * 2 + 1];
#pragma unroll
        for (int i = 0; i < 4; ++i) {
            float a = hs[(rg * 4 + i) * HPAD + k];
            acc[i][0] += a * w0.x; acc[i][1] += a * w0.y;
            acc[i][2] += a * w0.z; acc[i][3] += a * w0.w;
            acc[i][4] += a * w1.x; acc[i][5] += a * w1.y;
            acc[i][6] += a * w1.z; acc[i][7] += a * w1.w;
        }
    }

    float4 b0 = ((const float4*)bias)[cg * 2];
    float4 b1 = ((const float4*)bias)[cg * 2 + 1];
#pragma unroll
    for (int i = 0; i < 4; ++i) {
        int row = block_row + rg * 4 + i;
        if (row < NN) {
            float s = inv_in[row];
            float4 o0 = make_float4(acc[i][0] * s + b0.x, acc[i][1] * s + b0.y,
                                    acc[i][2] * s + b0.z, acc[i][3] * s + b0.w);
            float4 o1 = make_float4(acc[i][4] * s + b1.x, acc[i][5] * s + b1.y,
                                    acc[i][6] * s + b1.z, acc[i][7] * s + b1.w);
            float4* op = (float4*)(out + row * DOUT + cg * 8);
            op[0] = o0;
            op[1] = o1;
        }
    }
}

extern "C" void kernel_launch(void* const* d_in, const int* in_sizes, int n_in,
                              void* d_out, int out_size, void* d_ws, size_t ws_size,
                              hipStream_t stream) {
    const float* feat      = (const float*)d_in[0];
    const float* edge_feat = (const float*)d_in[1];
    const int*   src       = (const int*)d_in[2];
    const int*   dst       = (const int*)d_in[3];
    const float* W         = (const float*)d_in[4];
    const float* bias      = (const float*)d_in[5];
    float* out = (float*)d_out;

    float* h    = (float*)d_ws;
    float* odeg = h + (size_t)NN * DIN;
    float* ideg = odeg + NN;

    // 1) zero h + degree counters (ws is poisoned 0xAA before every call)
    int n4 = (NN * 258) / 4;
    zero_kernel<<<(n4 + 255) / 256, 256, 0, stream>>>((float4*)d_ws, n4);

    // 2) degree histogram
    degree_kernel<<<(NE + 255) / 256, 256, 0, stream>>>(src, dst, odeg, ideg);

    // 3) deg -> rsqrt(clip(deg,1)) in place (both arrays, contiguous)
    norm_kernel<<<(2 * NN + 255) / 256, 256, 0, stream>>>(odeg, 2 * NN);

    // 4) scatter-add messages into h
    int sblocks = (NE * 64) / 256;   // exact: 200000
    scatter_kernel<<<sblocks, 256, 0, stream>>>(feat, edge_feat, src, dst, odeg, h);

    // 5) GEMM + in-degree scale + bias
    gemm_kernel<<<(NN + 31) / 32, 256, 0, stream>>>(h, W, bias, ideg, out);
}

// Round 2
// 706.831 us; speedup vs baseline: 4.4016x; 4.4016x over previous
//
#include <hip/hip_runtime.h>

// Problem constants (match setup_inputs)
#define NN 50000      // nodes
#define NE 800000     // edges
#define DIN 256       // 192 + 64
#define DOUT 256

// ---------------------------------------------------------------------------
// ws layout (4-byte elements):
//   h        [NN*256]  floats
//   in_cnt   [NN]      int   (in-degree counts; scan input)
//   out_cnt  [NN]      int
//   cursor   [NN]      int   (fill cursors, zeroed)
//   row_off  [NN+1]    int   (CSR row offsets by dst)
//   odeg_inv [NN]      float (rsqrt(max(out_deg,1)))
//   perm     [NE]      int   (edge ids sorted by dst)
//   bsum     [256]     int   (scan block sums)
// Total ~13.8M elems = 55.2 MB
// ---------------------------------------------------------------------------

__global__ __launch_bounds__(256) void zero_meta(int* __restrict__ p, int n) {
    int i = blockIdx.x * 256 + threadIdx.x;
    if (i < n) p[i] = 0;
}

__global__ __launch_bounds__(256) void count_kernel(const int* __restrict__ src,
                                                    const int* __restrict__ dst,
                                                    int* __restrict__ in_cnt,
                                                    int* __restrict__ out_cnt) {
    int e = blockIdx.x * 256 + threadIdx.x;
    if (e < NE) {
        atomicAdd(in_cnt + dst[e], 1);
        atomicAdd(out_cnt + src[e], 1);
    }
}

// Per-block exclusive scan of in_cnt (256 elems/block) -> row_off, block totals -> bsum
__global__ __launch_bounds__(256) void scan1(const int* __restrict__ cnt,
                                             int* __restrict__ row_off,
                                             int* __restrict__ bsum) {
    __shared__ int tmp[256];
    int tid = threadIdx.x;
    int i = blockIdx.x * 256 + tid;
    int v = (i < NN) ? cnt[i] : 0;
    tmp[tid] = v;
    __syncthreads();
#pragma unroll
    for (int off = 1; off < 256; off <<= 1) {
        int t = (tid >= off) ? tmp[tid - off] : 0;
        __syncthreads();
        if (tid >= off) tmp[tid] += t;
        __syncthreads();
    }
    if (i < NN) row_off[i] = tmp[tid] - v;   // exclusive
    if (tid == 255) bsum[blockIdx.x] = tmp[255];
}

// Single-block exclusive scan of 196 block sums (in place)
__global__ __launch_bounds__(256) void scan2(int* __restrict__ bsum, int nb) {
    __shared__ int tmp[256];
    int tid = threadIdx.x;
    int v = (tid < nb) ? bsum[tid] : 0;
    tmp[tid] = v;
    __syncthreads();
#pragma unroll
    for (int off = 1; off < 256; off <<= 1) {
        int t = (tid >= off) ? tmp[tid - off] : 0;
        __syncthreads();
        if (tid >= off) tmp[tid] += t;
        __syncthreads();
    }
    if (tid < nb) bsum[tid] = tmp[tid] - v;  // exclusive
}

__global__ __launch_bounds__(256) void scan3(int* __restrict__ row_off,
                                             const int* __restrict__ bsum) {
    int i = blockIdx.x * 256 + threadIdx.x;
    if (i < NN) row_off[i] += bsum[i >> 8];
    if (i == NN) row_off[NN] = NE;
}

__global__ __launch_bounds__(256) void norm_out(const int* __restrict__ out_cnt,
                                                float* __restrict__ odeg_inv) {
    int i = blockIdx.x * 256 + threadIdx.x;
    if (i < NN) odeg_inv[i] = rsqrtf((float)max(out_cnt[i], 1));
}

__global__ __launch_bounds__(256) void fill_kernel(const int* __restrict__ dst,
                                                   const int* __restrict__ row_off,
                                                   int* __restrict__ cursor,
                                                   int* __restrict__ perm) {
    int e = blockIdx.x * 256 + threadIdx.x;
    if (e < NE) {
        int d = dst[e];
        int pos = atomicAdd(cursor + d, 1);
        perm[row_off[d] + pos] = e;
    }
}

// One wave (64 lanes) per dst node; lane owns one float4 column of the
// 256-wide message row. Lanes 0..47 gather feat_n[src], 48..63 gather
// edge_feat[e]. No atomics: h row written exactly once.
__global__ __launch_bounds__(256) void aggregate_kernel(const float* __restrict__ feat,
                                                        const float* __restrict__ edge_feat,
                                                        const int* __restrict__ src,
                                                        const int* __restrict__ row_off,
                                                        const float* __restrict__ odeg_inv,
                                                        const int* __restrict__ perm,
                                                        float* __restrict__ h) {
    int node = blockIdx.x * 4 + (threadIdx.x >> 6);
    int lane = threadIdx.x & 63;
    if (node >= NN) return;
    int start = row_off[node];
    int end   = row_off[node + 1];

    float4 acc = make_float4(0.f, 0.f, 0.f, 0.f);
    const float4* feat4 = (const float4*)feat;
    const float4* ef4   = (const float4*)edge_feat;

    // 1-deep pipeline on the perm->src dependent chain
    int e = 0, s = 0;
    if (start < end) { e = perm[start]; s = src[e]; }
    for (int i = start; i < end; ++i) {
        int e_cur = e, s_cur = s;
        if (i + 1 < end) { e = perm[i + 1]; s = src[e]; }
        if (lane < 48) {
            float4 v = feat4[(size_t)s_cur * 48 + lane];
            float sc = odeg_inv[s_cur];
            acc.x += v.x * sc; acc.y += v.y * sc;
            acc.z += v.z * sc; acc.w += v.w * sc;
        } else {
            float4 v = ef4[(size_t)e_cur * 16 + (lane - 48)];
            acc.x += v.x; acc.y += v.y; acc.z += v.z; acc.w += v.w;
        }
    }
    ((float4*)h)[(size_t)node * 64 + lane] = acc;
}

// rst = (h @ W) * rsqrt(max(in_deg,1))[:,None] + bias
#define HPAD 260
__global__ __launch_bounds__(256) void gemm_kernel(const float* __restrict__ h,
                                                   const float* __restrict__ W,
                                                   const float* __restrict__ bias,
                                                   const int* __restrict__ row_off,
                                                   float* __restrict__ out) {
    __shared__ float hs[32 * HPAD];
    int block_row = blockIdx.x * 32;

    for (int i = threadIdx.x; i < 32 * 64; i += 256) {
        int r = i >> 6, c4 = i & 63;
        int row = block_row + r;
        float4 v = make_float4(0.f, 0.f, 0.f, 0.f);
        if (row < NN) v = ((const float4*)h)[(size_t)row * 64 + c4];
        *(float4*)&hs[r * HPAD + c4 * 4] = v;
    }
    __syncthreads();

    int cg = threadIdx.x & 31;   // cols cg*8 .. cg*8+7
    int rg = threadIdx.x >> 5;   // rows rg*4 .. rg*4+3

    float acc[4][8];
#pragma unroll
    for (int i = 0; i < 4; ++i)
#pragma unroll
        for (int j = 0; j < 8; ++j) acc[i][j] = 0.f;

    const float4* W4 = (const float4*)W;
    for (int k = 0; k < DIN; ++k) {
        float4 w0 = W4[k * 64 + cg * 2];
        float4 w1 = W4[k * 64 + cg * 2 + 1];
#pragma unroll
        for (int i = 0; i < 4; ++i) {
            float a = hs[(rg * 4 + i) * HPAD + k];
            acc[i][0] += a * w0.x; acc[i][1] += a * w0.y;
            acc[i][2] += a * w0.z; acc[i][3] += a * w0.w;
            acc[i][4] += a * w1.x; acc[i][5] += a * w1.y;
            acc[i][6] += a * w1.z; acc[i][7] += a * w1.w;
        }
    }

    float4 b0 = ((const float4*)bias)[cg * 2];
    float4 b1 = ((const float4*)bias)[cg * 2 + 1];
#pragma unroll
    for (int i = 0; i < 4; ++i) {
        int row = block_row + rg * 4 + i;
        if (row < NN) {
            int deg = row_off[row + 1] - row_off[row];
            float s = rsqrtf((float)max(deg, 1));
            float4 o0 = make_float4(acc[i][0] * s + b0.x, acc[i][1] * s + b0.y,
                                    acc[i][2] * s + b0.z, acc[i][3] * s + b0.w);
            float4 o1 = make_float4(acc[i][4] * s + b1.x, acc[i][5] * s + b1.y,
                                    acc[i][6] * s + b1.z, acc[i][7] * s + b1.w);
            float4* op = (float4*)(out + (size_t)row * DOUT + cg * 8);
            op[0] = o0;
            op[1] = o1;
        }
    }
}

extern "C" void kernel_launch(void* const* d_in, const int* in_sizes, int n_in,
                              void* d_out, int out_size, void* d_ws, size_t ws_size,
                              hipStream_t stream) {
    const float* feat      = (const float*)d_in[0];
    const float* edge_feat = (const float*)d_in[1];
    const int*   src       = (const int*)d_in[2];
    const int*   dst       = (const int*)d_in[3];
    const float* W         = (const float*)d_in[4];
    const float* bias      = (const float*)d_in[5];
    float* out = (float*)d_out;

    float* h        = (float*)d_ws;
    int*   in_cnt   = (int*)(h + (size_t)NN * DIN);
    int*   out_cnt  = in_cnt + NN;
    int*   cursor   = out_cnt + NN;
    int*   row_off  = cursor + NN;
    float* odeg_inv = (float*)(row_off + NN + 1);
    int*   perm     = (int*)(odeg_inv + NN);
    int*   bsum     = perm + NE;

    const int SCAN_BLOCKS = (NN + 255) / 256;   // 196

    // 1) zero in_cnt/out_cnt/cursor (contiguous 3*NN ints)
    zero_meta<<<(3 * NN + 255) / 256, 256, 0, stream>>>(in_cnt, 3 * NN);

    // 2) degree histograms (int atomics)
    count_kernel<<<(NE + 255) / 256, 256, 0, stream>>>(src, dst, in_cnt, out_cnt);

    // 3-5) exclusive scan of in_cnt -> row_off
    scan1<<<SCAN_BLOCKS, 256, 0, stream>>>(in_cnt, row_off, bsum);
    scan2<<<1, 256, 0, stream>>>(bsum, SCAN_BLOCKS);
    scan3<<<(NN + 256) / 256, 256, 0, stream>>>(row_off, bsum);

    // 6) out-degree normalization factors
    norm_out<<<(NN + 255) / 256, 256, 0, stream>>>(out_cnt, odeg_inv);

    // 7) CSR fill (edge permutation by dst)
    fill_kernel<<<(NE + 255) / 256, 256, 0, stream>>>(dst, row_off, cursor, perm);

    // 8) gather-style aggregation, one wave per node, no atomics
    aggregate_kernel<<<(NN + 3) / 4, 256, 0, stream>>>(feat, edge_feat, src, row_off,
                                                       odeg_inv, perm, h);

    // 9) GEMM + in-degree scale + bias
    gemm_kernel<<<(NN + 31) / 32, 256, 0, stream>>>(h, W, bias, row_off, out);
}

// Round 3
// 615.876 us; speedup vs baseline: 5.0517x; 1.1477x over previous
//
#include <hip/hip_runtime.h>

// Problem constants (match setup_inputs)
#define NN 50000      // nodes
#define NE 800000     // edges
#define DIN 256       // 192 + 64
#define DOUT 256

// ---------------------------------------------------------------------------
// ws layout (4-byte elements):
//   h        [NN*256]   floats
//   row_off  [NN+2]     int   (CSR row offsets by dst; +1 pad for 8B align)
//   odeg_inv [NN]       float
//   cursor   [NN]       int   (fill cursors, init = row_off)
//   bsum     [256]      int   (scan block sums)
//   perm2    [NE] int2  (= 2*NE ints).  First 2*NN ints of this region double
//                        as in_cnt/out_cnt early (dead before fill writes).
// Total = 12,950,258 + 1,600,000 ints = 58.2 MB
// ---------------------------------------------------------------------------

__global__ __launch_bounds__(256) void zero_meta(int* __restrict__ p, int n) {
    int i = blockIdx.x * 256 + threadIdx.x;
    if (i < n) p[i] = 0;
}

__global__ __launch_bounds__(256) void count_kernel(const int* __restrict__ src,
                                                    const int* __restrict__ dst,
                                                    int* __restrict__ in_cnt,
                                                    int* __restrict__ out_cnt) {
    int e = blockIdx.x * 256 + threadIdx.x;
    if (e < NE) {
        atomicAdd(in_cnt + dst[e], 1);
        atomicAdd(out_cnt + src[e], 1);
    }
}

// Per-block exclusive scan of in_cnt (256/block) -> row_off, block totals -> bsum
__global__ __launch_bounds__(256) void scan1(const int* __restrict__ cnt,
                                             int* __restrict__ row_off,
                                             int* __restrict__ bsum) {
    __shared__ int tmp[256];
    int tid = threadIdx.x;
    int i = blockIdx.x * 256 + tid;
    int v = (i < NN) ? cnt[i] : 0;
    tmp[tid] = v;
    __syncthreads();
#pragma unroll
    for (int off = 1; off < 256; off <<= 1) {
        int t = (tid >= off) ? tmp[tid - off] : 0;
        __syncthreads();
        if (tid >= off) tmp[tid] += t;
        __syncthreads();
    }
    if (i < NN) row_off[i] = tmp[tid] - v;   // exclusive
    if (tid == 255) bsum[blockIdx.x] = tmp[255];
}

__global__ __launch_bounds__(256) void scan2(int* __restrict__ bsum, int nb) {
    __shared__ int tmp[256];
    int tid = threadIdx.x;
    int v = (tid < nb) ? bsum[tid] : 0;
    tmp[tid] = v;
    __syncthreads();
#pragma unroll
    for (int off = 1; off < 256; off <<= 1) {
        int t = (tid >= off) ? tmp[tid - off] : 0;
        __syncthreads();
        if (tid >= off) tmp[tid] += t;
        __syncthreads();
    }
    if (tid < nb) bsum[tid] = tmp[tid] - v;  // exclusive
}

// Finish scan; also seed cursor = row_off so fill's atomicAdd returns absolute pos.
__global__ __launch_bounds__(256) void scan3(int* __restrict__ row_off,
                                             int* __restrict__ cursor,
                                             const int* __restrict__ bsum) {
    int i = blockIdx.x * 256 + threadIdx.x;
    if (i < NN) {
        int v = row_off[i] + bsum[i >> 8];
        row_off[i] = v;
        cursor[i] = v;
    }
    if (i == NN) row_off[NN] = NE;
}

__global__ __launch_bounds__(256) void norm_out(const int* __restrict__ out_cnt,
                                                float* __restrict__ odeg_inv) {
    int i = blockIdx.x * 256 + threadIdx.x;
    if (i < NN) odeg_inv[i] = rsqrtf((float)max(out_cnt[i], 1));
}

// CSR fill: perm2[pos] = (edge id, src[e]).  src gathered here (coalesced read)
// so the aggregate loop has one less dependent-load level.
__global__ __launch_bounds__(256) void fill_kernel(const int* __restrict__ src,
                                                   const int* __restrict__ dst,
                                                   int* __restrict__ cursor,
                                                   int2* __restrict__ perm2) {
    int e = blockIdx.x * 256 + threadIdx.x;
    if (e < NE) {
        int d = dst[e];
        int pos = atomicAdd(cursor + d, 1);
        perm2[pos] = make_int2(e, src[e]);
    }
}

// One wave per dst node; lane owns one float4 column of the 256-wide row.
// Branchless single-load-path; 4-deep unroll for memory-level parallelism.
__global__ __launch_bounds__(256) void aggregate_kernel(const float* __restrict__ feat,
                                                        const float* __restrict__ edge_feat,
                                                        const int* __restrict__ row_off,
                                                        const float* __restrict__ odeg_inv,
                                                        const int2* __restrict__ perm2,
                                                        float* __restrict__ h) {
    int node = blockIdx.x * 4 + (threadIdx.x >> 6);
    int lane = threadIdx.x & 63;
    if (node >= NN) return;
    int start = row_off[node];
    int end   = row_off[node + 1];

    bool isF = lane < 48;
    const float* base = isF ? feat : edge_feat;
    int stride = isF ? 192 : 64;                 // floats per source row
    int loff   = isF ? lane * 4 : (lane - 48) * 4;

    float4 acc = make_float4(0.f, 0.f, 0.f, 0.f);
    int i = start;
    for (; i + 4 <= end; i += 4) {
        int2 p0 = perm2[i + 0];
        int2 p1 = perm2[i + 1];
        int2 p2 = perm2[i + 2];
        int2 p3 = perm2[i + 3];
        int i0 = isF ? p0.y : p0.x;
        int i1 = isF ? p1.y : p1.x;
        int i2 = isF ? p2.y : p2.x;
        int i3 = isF ? p3.y : p3.x;
        // 4 independent vector gathers in flight
        float4 v0 = *(const float4*)(base + (size_t)i0 * stride + loff);
        float4 v1 = *(const float4*)(base + (size_t)i1 * stride + loff);
        float4 v2 = *(const float4*)(base + (size_t)i2 * stride + loff);
        float4 v3 = *(const float4*)(base + (size_t)i3 * stride + loff);
        float s0 = odeg_inv[p0.y]; if (!isF) s0 = 1.f;
        float s1 = odeg_inv[p1.y]; if (!isF) s1 = 1.f;
        float s2 = odeg_inv[p2.y]; if (!isF) s2 = 1.f;
        float s3 = odeg_inv[p3.y]; if (!isF) s3 = 1.f;
        acc.x = fmaf(v0.x, s0, acc.x); acc.y = fmaf(v0.y, s0, acc.y);
        acc.z = fmaf(v0.z, s0, acc.z); acc.w = fmaf(v0.w, s0, acc.w);
        acc.x = fmaf(v1.x, s1, acc.x); acc.y = fmaf(v1.y, s1, acc.y);
        acc.z = fmaf(v1.z, s1, acc.z); acc.w = fmaf(v1.w, s1, acc.w);
        acc.x = fmaf(v2.x, s2, acc.x); acc.y = fmaf(v2.y, s2, acc.y);
        acc.z = fmaf(v2.z, s2, acc.z); acc.w = fmaf(v2.w, s2, acc.w);
        acc.x = fmaf(v3.x, s3, acc.x); acc.y = fmaf(v3.y, s3, acc.y);
        acc.z = fmaf(v3.z, s3, acc.z); acc.w = fmaf(v3.w, s3, acc.w);
    }
    for (; i < end; ++i) {
        int2 p = perm2[i];
        int idx = isF ? p.y : p.x;
        float4 v = *(const float4*)(base + (size_t)idx * stride + loff);
        float s = odeg_inv[p.y]; if (!isF) s = 1.f;
        acc.x = fmaf(v.x, s, acc.x); acc.y = fmaf(v.y, s, acc.y);
        acc.z = fmaf(v.z, s, acc.z); acc.w = fmaf(v.w, s, acc.w);
    }
    ((float4*)h)[(size_t)node * 64 + lane] = acc;
}

// rst = (h @ W) * rsqrt(max(in_deg,1))[:,None] + bias
// 32 rows x 256 cols per block; inner loop in k-chunks of 4 with ds_read_b128.
#define HPAD 260
__global__ __launch_bounds__(256) void gemm_kernel(const float* __restrict__ h,
                                                   const float* __restrict__ W,
                                                   const float* __restrict__ bias,
                                                   const int* __restrict__ row_off,
                                                   float* __restrict__ out) {
    __shared__ float hs[32 * HPAD];
    int block_row = blockIdx.x * 32;

    for (int i = threadIdx.x; i < 32 * 64; i += 256) {
        int r = i >> 6, c4 = i & 63;
        int row = block_row + r;
        float4 v = make_float4(0.f, 0.f, 0.f, 0.f);
        if (row < NN) v = ((const float4*)h)[(size_t)row * 64 + c4];
        *(float4*)&hs[r * HPAD + c4 * 4] = v;
    }
    __syncthreads();

    int cg = threadIdx.x & 31;   // cols cg*8 .. cg*8+7
    int rg = threadIdx.x >> 5;   // rows rg*4 .. rg*4+3

    float acc[4][8];
#pragma unroll
    for (int i = 0; i < 4; ++i)
#pragma unroll
        for (int j = 0; j < 8; ++j) acc[i][j] = 0.f;

    const float4* W4 = (const float4*)W;
    for (int k4 = 0; k4 < 64; ++k4) {
        float4 a[4];
#pragma unroll
        for (int i = 0; i < 4; ++i)
            a[i] = *(const float4*)&hs[(rg * 4 + i) * HPAD + k4 * 4];
#pragma unroll
        for (int kk = 0; kk < 4; ++kk) {
            int k = k4 * 4 + kk;
            float4 w0 = W4[k * 64 + cg * 2];
            float4 w1 = W4[k * 64 + cg * 2 + 1];
#pragma unroll
            for (int i = 0; i < 4; ++i) {
                float av = ((const float*)&a[i])[kk];
                acc[i][0] = fmaf(av, w0.x, acc[i][0]);
                acc[i][1] = fmaf(av, w0.y, acc[i][1]);
                acc[i][2] = fmaf(av, w0.z, acc[i][2]);
                acc[i][3] = fmaf(av, w0.w, acc[i][3]);
                acc[i][4] = fmaf(av, w1.x, acc[i][4]);
                acc[i][5] = fmaf(av, w1.y, acc[i][5]);
                acc[i][6] = fmaf(av, w1.z, acc[i][6]);
                acc[i][7] = fmaf(av, w1.w, acc[i][7]);
            }
        }
    }

    float4 b0 = ((const float4*)bias)[cg * 2];
    float4 b1 = ((const float4*)bias)[cg * 2 + 1];
#pragma unroll
    for (int i = 0; i < 4; ++i) {
        int row = block_row + rg * 4 + i;
        if (row < NN) {
            int deg = row_off[row + 1] - row_off[row];
            float s = rsqrtf((float)max(deg, 1));
            float4 o0 = make_float4(acc[i][0] * s + b0.x, acc[i][1] * s + b0.y,
                                    acc[i][2] * s + b0.z, acc[i][3] * s + b0.w);
            float4 o1 = make_float4(acc[i][4] * s + b1.x, acc[i][5] * s + b1.y,
                                    acc[i][6] * s + b1.z, acc[i][7] * s + b1.w);
            float4* op = (float4*)(out + (size_t)row * DOUT + cg * 8);
            op[0] = o0;
            op[1] = o1;
        }
    }
}

extern "C" void kernel_launch(void* const* d_in, const int* in_sizes, int n_in,
                              void* d_out, int out_size, void* d_ws, size_t ws_size,
                              hipStream_t stream) {
    const float* feat      = (const float*)d_in[0];
    const float* edge_feat = (const float*)d_in[1];
    const int*   src       = (const int*)d_in[2];
    const int*   dst       = (const int*)d_in[3];
    const float* W         = (const float*)d_in[4];
    const float* bias      = (const float*)d_in[5];
    float* out = (float*)d_out;

    float* h        = (float*)d_ws;
    int*   row_off  = (int*)(h + (size_t)NN * DIN);     // NN+2 (pad to even)
    float* odeg_inv = (float*)(row_off + NN + 2);       // NN
    int*   cursor   = (int*)(odeg_inv + NN);            // NN
    int*   bsum     = cursor + NN;                      // 256
    int2*  perm2    = (int2*)(bsum + 256);              // NE int2
    // early-phase aliases over the perm2 region (dead before fill writes it)
    int*   in_cnt   = (int*)perm2;                      // NN
    int*   out_cnt  = in_cnt + NN;                      // NN

    const int SCAN_BLOCKS = (NN + 255) / 256;   // 196

    // 1) zero in_cnt/out_cnt (contiguous 2*NN ints)
    zero_meta<<<(2 * NN + 255) / 256, 256, 0, stream>>>(in_cnt, 2 * NN);

    // 2) degree histograms (int atomics)
    count_kernel<<<(NE + 255) / 256, 256, 0, stream>>>(src, dst, in_cnt, out_cnt);

    // 3-5) exclusive scan of in_cnt -> row_off (+ cursor seed)
    scan1<<<SCAN_BLOCKS, 256, 0, stream>>>(in_cnt, row_off, bsum);
    scan2<<<1, 256, 0, stream>>>(bsum, SCAN_BLOCKS);
    scan3<<<(NN + 256) / 256, 256, 0, stream>>>(row_off, cursor, bsum);

    // 6) out-degree normalization factors
    norm_out<<<(NN + 255) / 256, 256, 0, stream>>>(out_cnt, odeg_inv);

    // 7) CSR fill: (edge id, src) pairs sorted by dst
    fill_kernel<<<(NE + 255) / 256, 256, 0, stream>>>(src, dst, cursor, perm2);

    // 8) gather aggregation, one wave per node, no atomics, 4-deep MLP
    aggregate_kernel<<<(NN + 3) / 4, 256, 0, stream>>>(feat, edge_feat, row_off,
                                                       odeg_inv, perm2, h);

    // 9) GEMM + in-degree scale + bias
    gemm_kernel<<<(NN + 31) / 32, 256, 0, stream>>>(h, W, bias, row_off, out);
}

// Round 4
// 564.021 us; speedup vs baseline: 5.5161x; 1.0919x over previous
//
#include <hip/hip_runtime.h>

// Problem constants (match setup_inputs)
#define NN 50000      // nodes
#define NE 800000     // edges
#define DIN 256       // 192 + 64
#define DOUT 256

typedef __attribute__((ext_vector_type(8))) short bf16x8;  // 8 bf16 = 4 VGPRs
typedef __attribute__((ext_vector_type(4))) float f32x4;   // MFMA acc

__device__ __forceinline__ unsigned short f2bf(float x) {
    unsigned int u = __builtin_bit_cast(unsigned int, x);
    u += 0x7fffu + ((u >> 16) & 1u);        // round-to-nearest-even
    return (unsigned short)(u >> 16);
}

// ---------------------------------------------------------------------------
// ws layout (4-byte words):
//   h_bf     [NN*256]  bf16  (= NN*128 words, 25.6 MB)
//   wt_bf    [256*256] bf16  (= 32768 words; W transposed: wt[n][k]=W[k][n])
//   row_off  [NN+2]    int
//   odeg_inv [NN]      float
//   cursor   [NN]      int
//   bsum     [256]     int
//   perm2    [NE]      int2  (first 2*NN ints alias in_cnt/out_cnt early)
// ---------------------------------------------------------------------------

__global__ __launch_bounds__(256) void zero_meta(int* __restrict__ p, int n) {
    int i = blockIdx.x * 256 + threadIdx.x;
    if (i < n) p[i] = 0;
}

__global__ __launch_bounds__(256) void count_kernel(const int* __restrict__ src,
                                                    const int* __restrict__ dst,
                                                    int* __restrict__ in_cnt,
                                                    int* __restrict__ out_cnt) {
    int e = blockIdx.x * 256 + threadIdx.x;
    if (e < NE) {
        atomicAdd(in_cnt + dst[e], 1);
        atomicAdd(out_cnt + src[e], 1);
    }
}

__global__ __launch_bounds__(256) void scan1(const int* __restrict__ cnt,
                                             int* __restrict__ row_off,
                                             int* __restrict__ bsum) {
    __shared__ int tmp[256];
    int tid = threadIdx.x;
    int i = blockIdx.x * 256 + tid;
    int v = (i < NN) ? cnt[i] : 0;
    tmp[tid] = v;
    __syncthreads();
#pragma unroll
    for (int off = 1; off < 256; off <<= 1) {
        int t = (tid >= off) ? tmp[tid - off] : 0;
        __syncthreads();
        if (tid >= off) tmp[tid] += t;
        __syncthreads();
    }
    if (i < NN) row_off[i] = tmp[tid] - v;   // exclusive
    if (tid == 255) bsum[blockIdx.x] = tmp[255];
}

__global__ __launch_bounds__(256) void scan2(int* __restrict__ bsum, int nb) {
    __shared__ int tmp[256];
    int tid = threadIdx.x;
    int v = (tid < nb) ? bsum[tid] : 0;
    tmp[tid] = v;
    __syncthreads();
#pragma unroll
    for (int off = 1; off < 256; off <<= 1) {
        int t = (tid >= off) ? tmp[tid - off] : 0;
        __syncthreads();
        if (tid >= off) tmp[tid] += t;
        __syncthreads();
    }
    if (tid < nb) bsum[tid] = tmp[tid] - v;  // exclusive
}

// Finish row_off scan; seed cursor; fold in odeg_inv (out_cnt still live here).
__global__ __launch_bounds__(256) void scan3(int* __restrict__ row_off,
                                             int* __restrict__ cursor,
                                             float* __restrict__ odeg_inv,
                                             const int* __restrict__ out_cnt,
                                             const int* __restrict__ bsum) {
    int i = blockIdx.x * 256 + threadIdx.x;
    if (i < NN) {
        int v = row_off[i] + bsum[i >> 8];
        row_off[i] = v;
        cursor[i] = v;
        odeg_inv[i] = rsqrtf((float)max(out_cnt[i], 1));
    }
    if (i == NN) row_off[NN] = NE;
}

// W[k][n] fp32 -> wt[n][k] bf16
__global__ __launch_bounds__(256) void wconv(const float* __restrict__ W,
                                             unsigned short* __restrict__ wt) {
    int n = blockIdx.x, k = threadIdx.x;
    wt[n * 256 + k] = f2bf(W[k * 256 + n]);
}

// CSR fill: perm2[pos] = (edge id, src[e])
__global__ __launch_bounds__(256) void fill_kernel(const int* __restrict__ src,
                                                   const int* __restrict__ dst,
                                                   int* __restrict__ cursor,
                                                   int2* __restrict__ perm2) {
    int e = blockIdx.x * 256 + threadIdx.x;
    if (e < NE) {
        int d = dst[e];
        int pos = atomicAdd(cursor + d, 1);
        perm2[pos] = make_int2(e, src[e]);
    }
}

// One wave per dst node; lane owns one float4 column of the 256-wide row.
// Branchless 8-wide inner loop (clamped index + zero weight) for MLP.
// fp32 accumulate, single bf16 round at store.
__global__ __launch_bounds__(256) void aggregate_kernel(const float* __restrict__ feat,
                                                        const float* __restrict__ edge_feat,
                                                        const int* __restrict__ row_off,
                                                        const float* __restrict__ odeg_inv,
                                                        const int2* __restrict__ perm2,
                                                        unsigned short* __restrict__ h_bf) {
    int node = blockIdx.x * 4 + (threadIdx.x >> 6);
    int lane = threadIdx.x & 63;
    if (node >= NN) return;
    int start = row_off[node];
    int end   = row_off[node + 1];

    bool isF = lane < 48;
    const float* base = isF ? feat : edge_feat;
    int stride = isF ? 192 : 64;
    int loff   = isF ? lane * 4 : (lane - 48) * 4;

    float4 acc = make_float4(0.f, 0.f, 0.f, 0.f);
    for (int i = start; i < end; i += 8) {
        int2 p[8];
        float4 v[8];
        float w[8];
#pragma unroll
        for (int j = 0; j < 8; ++j) {
            int ii = min(i + j, end - 1);
            p[j] = perm2[ii];
        }
#pragma unroll
        for (int j = 0; j < 8; ++j) {
            int idx = isF ? p[j].y : p[j].x;
            v[j] = *(const float4*)(base + (size_t)idx * stride + loff);
        }
#pragma unroll
        for (int j = 0; j < 8; ++j) {
            float s = isF ? odeg_inv[p[j].y] : 1.f;
            w[j] = (i + j < end) ? s : 0.f;
        }
#pragma unroll
        for (int j = 0; j < 8; ++j) {
            acc.x = fmaf(v[j].x, w[j], acc.x);
            acc.y = fmaf(v[j].y, w[j], acc.y);
            acc.z = fmaf(v[j].z, w[j], acc.z);
            acc.w = fmaf(v[j].w, w[j], acc.w);
        }
    }
    ushort4 o;
    o.x = f2bf(acc.x); o.y = f2bf(acc.y);
    o.z = f2bf(acc.z); o.w = f2bf(acc.w);
    *(ushort4*)(h_bf + (size_t)node * 256 + lane * 4) = o;
}

// MFMA GEMM: out = (h_bf @ W) * rsqrt(max(in_deg,1))[:,None] + bias
// Block = 16 rows x 256 cols; 4 waves side-by-side on cols (64 each).
// Wave: 4 col-tiles of 16x16 over K=256 in 8 steps of k=32. No LDS.
// A-frag: lane holds h[rbase + (lane&15)][k0 + (lane>>4)*8 + j]
// B-frag: lane holds W[k][cbase+t*16+(lane&15)] = wt[(col)][k...]
// C/D:    row = (lane>>4)*4 + reg, col = lane&15   [guide §3, m89-verified]
__global__ __launch_bounds__(256) void gemm_mfma(const unsigned short* __restrict__ h_bf,
                                                 const unsigned short* __restrict__ wt_bf,
                                                 const float* __restrict__ bias,
                                                 const int* __restrict__ row_off,
                                                 float* __restrict__ out) {
    int wave = threadIdx.x >> 6;
    int lane = threadIdx.x & 63;
    int m16  = lane & 15;
    int quad = lane >> 4;
    int rbase = blockIdx.x * 16;
    int cbase = wave * 64;

    const unsigned short* arow = h_bf + (size_t)(rbase + m16) * 256 + quad * 8;
    const unsigned short* b0p = wt_bf + (size_t)(cbase +  0 + m16) * 256 + quad * 8;
    const unsigned short* b1p = wt_bf + (size_t)(cbase + 16 + m16) * 256 + quad * 8;
    const unsigned short* b2p = wt_bf + (size_t)(cbase + 32 + m16) * 256 + quad * 8;
    const unsigned short* b3p = wt_bf + (size_t)(cbase + 48 + m16) * 256 + quad * 8;

    f32x4 acc0 = {0.f, 0.f, 0.f, 0.f};
    f32x4 acc1 = {0.f, 0.f, 0.f, 0.f};
    f32x4 acc2 = {0.f, 0.f, 0.f, 0.f};
    f32x4 acc3 = {0.f, 0.f, 0.f, 0.f};

#pragma unroll
    for (int k0 = 0; k0 < 256; k0 += 32) {
        bf16x8 a  = *(const bf16x8*)(arow + k0);
        bf16x8 b0 = *(const bf16x8*)(b0p + k0);
        bf16x8 b1 = *(const bf16x8*)(b1p + k0);
        bf16x8 b2 = *(const bf16x8*)(b2p + k0);
        bf16x8 b3 = *(const bf16x8*)(b3p + k0);
        acc0 = __builtin_amdgcn_mfma_f32_16x16x32_bf16(a, b0, acc0, 0, 0, 0);
        acc1 = __builtin_amdgcn_mfma_f32_16x16x32_bf16(a, b1, acc1, 0, 0, 0);
        acc2 = __builtin_amdgcn_mfma_f32_16x16x32_bf16(a, b2, acc2, 0, 0, 0);
        acc3 = __builtin_amdgcn_mfma_f32_16x16x32_bf16(a, b3, acc3, 0, 0, 0);
    }

    // in-degree scales for this lane's 4 output rows
    int grow0 = rbase + quad * 4;
    float s[4];
    int ro_prev = row_off[grow0];
#pragma unroll
    for (int r = 0; r < 4; ++r) {
        int nx = row_off[grow0 + r + 1];
        s[r] = rsqrtf((float)max(nx - ro_prev, 1));
        ro_prev = nx;
    }

    float bv0 = bias[cbase +  0 + m16];
    float bv1 = bias[cbase + 16 + m16];
    float bv2 = bias[cbase + 32 + m16];
    float bv3 = bias[cbase + 48 + m16];

#pragma unroll
    for (int r = 0; r < 4; ++r) {
        size_t rowoff = (size_t)(grow0 + r) * DOUT;
        out[rowoff + cbase +  0 + m16] = acc0[r] * s[r] + bv0;
        out[rowoff + cbase + 16 + m16] = acc1[r] * s[r] + bv1;
        out[rowoff + cbase + 32 + m16] = acc2[r] * s[r] + bv2;
        out[rowoff + cbase + 48 + m16] = acc3[r] * s[r] + bv3;
    }
}

extern "C" void kernel_launch(void* const* d_in, const int* in_sizes, int n_in,
                              void* d_out, int out_size, void* d_ws, size_t ws_size,
                              hipStream_t stream) {
    const float* feat      = (const float*)d_in[0];
    const float* edge_feat = (const float*)d_in[1];
    const int*   src       = (const int*)d_in[2];
    const int*   dst       = (const int*)d_in[3];
    const float* W         = (const float*)d_in[4];
    const float* bias      = (const float*)d_in[5];
    float* out = (float*)d_out;

    unsigned short* h_bf    = (unsigned short*)d_ws;                 // NN*256 bf16
    unsigned short* wt_bf   = h_bf + (size_t)NN * DIN;               // 256*256 bf16
    int*   row_off  = (int*)(wt_bf + 256 * 256);                     // NN+2
    float* odeg_inv = (float*)(row_off + NN + 2);                    // NN
    int*   cursor   = (int*)(odeg_inv + NN);                         // NN
    int*   bsum     = cursor + NN;                                   // 256
    int2*  perm2    = (int2*)(bsum + 256);                           // NE int2
    int*   in_cnt   = (int*)perm2;                                   // alias (early)
    int*   out_cnt  = in_cnt + NN;                                   // alias (early)

    const int SCAN_BLOCKS = (NN + 255) / 256;   // 196

    zero_meta<<<(2 * NN + 255) / 256, 256, 0, stream>>>(in_cnt, 2 * NN);
    count_kernel<<<(NE + 255) / 256, 256, 0, stream>>>(src, dst, in_cnt, out_cnt);
    scan1<<<SCAN_BLOCKS, 256, 0, stream>>>(in_cnt, row_off, bsum);
    scan2<<<1, 256, 0, stream>>>(bsum, SCAN_BLOCKS);
    scan3<<<(NN + 256) / 256, 256, 0, stream>>>(row_off, cursor, odeg_inv, out_cnt, bsum);
    wconv<<<256, 256, 0, stream>>>(W, wt_bf);
    fill_kernel<<<(NE + 255) / 256, 256, 0, stream>>>(src, dst, cursor, perm2);
    aggregate_kernel<<<(NN + 3) / 4, 256, 0, stream>>>(feat, edge_feat, row_off,
                                                       odeg_inv, perm2, h_bf);
    gemm_mfma<<<NN / 16, 256, 0, stream>>>(h_bf, wt_bf, bias, row_off, out);
}